// Round 1
// baseline (841.093 us; speedup 1.0000x reference)
//
#include <hip/hip_runtime.h>

// 2D Haar DWT, single level.
// Input:  x (8, 64, 512, 512) f32  -> BC = 512 images of 512x512
// Output: LL, LH, HL, HH each (8, 64, 256, 256) f32, concatenated in d_out.
//
// For 2x2 block p00 p01 / p10 p11 (rows 2h, 2h+1; cols 2w, 2w+1):
//   LL = (p00+p01+p10+p11)*0.5
//   LH = (p00+p01-p10-p11)*0.5
//   HL = (p00-p01+p10-p11)*0.5
//   HH = (p00-p01-p10+p11)*0.5

#define BC     512           // 8*64 images
#define W_IN   512
#define H_OUT  256
#define W_OUT  256
#define SUBBAND ((size_t)BC * H_OUT * W_OUT)   // 33,554,432 elems per subband

__global__ __launch_bounds__(256) void dwt2d_haar_kernel(
    const float* __restrict__ x, float* __restrict__ out)
{
    // Each thread: 4 output columns of one output row of one image.
    // 64 threads per output row; 256 rows; 512 images -> 8,388,608 threads.
    unsigned tid = blockIdx.x * blockDim.x + threadIdx.x;

    unsigned w4 = tid & 63;          // output col group (4 cols each)
    unsigned t  = tid >> 6;
    unsigned h  = t & (H_OUT - 1);   // output row
    unsigned bc = t >> 8;            // image index

    const float* row0 = x + ((size_t)bc << 18) + ((size_t)(h << 1) << 9) + (w4 << 3);
    const float* row1 = row0 + W_IN;

    float4 a0 = *reinterpret_cast<const float4*>(row0);      // cols 8w4 .. 8w4+3
    float4 a1 = *reinterpret_cast<const float4*>(row0 + 4);  // cols 8w4+4 .. +7
    float4 b0 = *reinterpret_cast<const float4*>(row1);
    float4 b1 = *reinterpret_cast<const float4*>(row1 + 4);

    float4 ll, lh, hl, hh;

    // element 0: pairs (a0.x,a0.y) / (b0.x,b0.y)
    {
        float sp = a0.x + a0.y, sm = a0.x - a0.y;
        float tp = b0.x + b0.y, tm = b0.x - b0.y;
        ll.x = (sp + tp) * 0.5f;  lh.x = (sp - tp) * 0.5f;
        hl.x = (sm + tm) * 0.5f;  hh.x = (sm - tm) * 0.5f;
    }
    // element 1: (a0.z,a0.w) / (b0.z,b0.w)
    {
        float sp = a0.z + a0.w, sm = a0.z - a0.w;
        float tp = b0.z + b0.w, tm = b0.z - b0.w;
        ll.y = (sp + tp) * 0.5f;  lh.y = (sp - tp) * 0.5f;
        hl.y = (sm + tm) * 0.5f;  hh.y = (sm - tm) * 0.5f;
    }
    // element 2: (a1.x,a1.y) / (b1.x,b1.y)
    {
        float sp = a1.x + a1.y, sm = a1.x - a1.y;
        float tp = b1.x + b1.y, tm = b1.x - b1.y;
        ll.z = (sp + tp) * 0.5f;  lh.z = (sp - tp) * 0.5f;
        hl.z = (sm + tm) * 0.5f;  hh.z = (sm - tm) * 0.5f;
    }
    // element 3: (a1.z,a1.w) / (b1.z,b1.w)
    {
        float sp = a1.z + a1.w, sm = a1.z - a1.w;
        float tp = b1.z + b1.w, tm = b1.z - b1.w;
        ll.w = (sp + tp) * 0.5f;  lh.w = (sp - tp) * 0.5f;
        hl.w = (sm + tm) * 0.5f;  hh.w = (sm - tm) * 0.5f;
    }

    size_t obase = ((size_t)bc << 16) + ((size_t)h << 8) + (w4 << 2);
    *reinterpret_cast<float4*>(out + obase)                = ll;
    *reinterpret_cast<float4*>(out + SUBBAND + obase)      = lh;
    *reinterpret_cast<float4*>(out + 2 * SUBBAND + obase)  = hl;
    *reinterpret_cast<float4*>(out + 3 * SUBBAND + obase)  = hh;
}

extern "C" void kernel_launch(void* const* d_in, const int* in_sizes, int n_in,
                              void* d_out, int out_size, void* d_ws, size_t ws_size,
                              hipStream_t stream) {
    const float* x = (const float*)d_in[0];
    float* out = (float*)d_out;

    // 512 images * 256 rows * 64 threads/row = 8,388,608 threads
    const unsigned total = BC * H_OUT * 64;
    const unsigned block = 256;
    const unsigned grid = total / block;   // 32768

    dwt2d_haar_kernel<<<grid, block, 0, stream>>>(x, out);
}